// Round 9
// baseline (242.289 us; speedup 1.0000x reference)
//
#include <hip/hip_runtime.h>
#include <math.h>

// Model dims
#define BB 8
#define TT 150
#define DD 30
#define HH 5
#define HD 6
#define LL 3
#define NI 40            // B*H heads per stream
#define ROWF (TT*BB*DD)  // 36000 floats per [T,B,D] buffer
#define RSTR 8           // padded LDS row stride in halves (16B -> ds_read_b128)
#define NR 152           // padded row count (150 data + vbar + zero)

typedef _Float16 half8 __attribute__((ext_vector_type(8)));
typedef float f32x16 __attribute__((ext_vector_type(16)));

__device__ __forceinline__ float wsum(float v) {
    #pragma unroll
    for (int m = 32; m > 0; m >>= 1) v += __shfl_xor(v, m, 64);
    return v;
}

__device__ __forceinline__ float max3f(float a, float b, float c) {
    return fmaxf(fmaxf(a, b), c);   // clang fuses to v_max3_f32; max is exactly associative
}

// Merged front end: one dispatch, 2400 blocks.
//  blocks [0,1800): (po, tb-chunk) -> inline a/v proj (13KB LDS weights) -> LN -> k,v
//  blocks [1800,2400): (s, tb-chunk) -> inline l proj (chunked 18KB Wl stage,
//    exact proj3 half-split order) -> write pl (s==0) -> LN -> q (layer 0)
union FMem {
    struct { float WaS[2250]; float WvS[1050]; float iwS[1800];
             float xa[4][80]; float xv[4][40];
             float rr[2][4][32]; float xn[4][2][32]; } kv;      // ~22 KB
    struct { float Wc[30 * 151]; float iwS[900]; float xl[4][304];
             float rr[4][32]; float xn[4][32]; } qp;            // ~27.6 KB
};

__global__ __launch_bounds__(256) void front_kernel(
    const float* __restrict__ x_l, const float* __restrict__ x_a, const float* __restrict__ x_v,
    const float* __restrict__ Wl, const float* __restrict__ Wa, const float* __restrict__ Wv,
    const float* __restrict__ in_w, const float* __restrict__ in_b,
    const float* __restrict__ n1g, const float* __restrict__ n1b,
    float* __restrict__ pl,
    _Float16* __restrict__ k_all, _Float16* __restrict__ v_all, _Float16* __restrict__ q) {
    int blk = blockIdx.x;                   // [0,2400)
    int tid = threadIdx.x;
    int w = tid >> 6, lane = tid & 63;
    __shared__ FMem sm;

    if (blk < 1800) {
        int po = blk / 300;                 // s*LL+l
        int s = po / LL;
        int tb = (blk % 300) * 4 + w;       // [0,1200)
        int t = tb / BB, b = tb % BB;
        // stage weights (coalesced)
        for (int j = tid; j < 2220; j += 256) sm.kv.WaS[(j / 74) * 75 + (j % 74)] = Wa[j];
        for (int j = tid; j < 1050; j += 256) sm.kv.WvS[j] = Wv[j];
        for (int j = tid; j < 1800; j += 256) sm.kv.iwS[j] = in_w[(size_t)po * 2700 + 900 + j];
        const float* xpa = x_a + ((size_t)b * TT + t) * 74;
        const float* xpv = x_v + ((size_t)b * TT + t) * 35;
        for (int j = lane; j < 74; j += 64) sm.kv.xa[w][j] = xpa[j];
        if (lane < 35) sm.kv.xv[w][lane] = xpv[lane];
        __syncthreads();
        // a/v projections, exact proj3 half-split order
        int d = lane >> 1, jh = lane & 1;
        int dc = d < DD ? d : 0;
        {
            const float* wr = sm.kv.WaS + dc * 75;
            int j0 = jh ? 37 : 0, j1 = jh ? 74 : 37;
            float acc = 0.f;
            for (int j = j0; j < j1; j++) acc += sm.kv.xa[w][j] * wr[j];
            acc += __shfl_xor(acc, 1, 64);
            if (jh == 0 && d < DD) sm.kv.rr[0][w][d] = acc;     // pa
        }
        {
            const float* wr = sm.kv.WvS + dc * 35;
            int j0 = jh ? 17 : 0, j1 = jh ? 35 : 17;
            float acc = 0.f;
            for (int j = j0; j < j1; j++) acc += sm.kv.xv[w][j] * wr[j];
            acc += __shfl_xor(acc, 1, 64);
            if (jh == 0 && d < DD) sm.kv.rr[1][w][d] = acc;     // pv
        }
        __syncthreads();
        // LN (kvq0 order: r=0 is xk, r=1 is xv of the stream)
        const float* g  = n1g + (size_t)po * 30;
        const float* bb = n1b + (size_t)po * 30;
        int sel0 = (s == 0) ? 0 : 1;        // xk = pa (s=0) / pv (s=1)
        for (int r = 0; r < 2; r++) {
            int src = (r == 0) ? sel0 : (1 - sel0);
            float xval = (lane < 30) ? sm.kv.rr[src][w][lane] : 0.f;
            float mean = wsum(xval) * (1.f / 30.f);
            float dv = (lane < 30) ? (xval - mean) : 0.f;
            float var = wsum(dv * dv) * (1.f / 30.f);
            float inv = rsqrtf(var + 1e-5f);
            if (lane < 30) sm.kv.xn[w][r][lane] = dv * inv * g[lane] + bb[lane];
        }
        __syncthreads();
        if (lane < 60) {
            int which = lane / 30, dd = lane % 30;
            const float* wr = sm.kv.iwS + lane * 30;
            const float* xv2 = sm.kv.xn[w][which];
            float acc = 0.f;
            #pragma unroll 6
            for (int j = 0; j < 30; j++) acc += wr[j] * xv2[j];
            acc += in_b[po * 90 + 30 + lane];
            int i = b * HH + dd / HD, hd = dd % HD;
            _Float16* dst = which ? v_all : k_all;
            size_t row = (((size_t)po * NI + i) * TT + t) * 8;
            dst[row + hd] = (_Float16)acc;
            if (hd < 2) dst[row + 6 + hd] = (_Float16)0.f;
        }
    } else {
        int r2 = blk - 1800;                // [0,600)
        int s = r2 / 300;
        int tb = (r2 % 300) * 4 + w;
        int t = tb / BB, b = tb % BB;
        int po = s * LL;                    // layer 0
        for (int j = tid; j < 900; j += 256) sm.qp.iwS[j] = in_w[(size_t)po * 2700 + j];
        const float* xpl = x_l + ((size_t)b * TT + t) * 300;
        for (int j = lane; j < 300; j += 64) sm.qp.xl[w][j] = xpl[j];
        // chunk 0: Wl columns 0..149
        for (int j = tid; j < 4500; j += 256)
            sm.qp.Wc[(j / 150) * 151 + (j % 150)] = Wl[(size_t)(j / 150) * 300 + (j % 150)];
        __syncthreads();
        int d = lane >> 1, jh = lane & 1;
        int dc = d < DD ? d : 0;
        float acc = 0.f;
        if (jh == 0) {
            const float* wr = sm.qp.Wc + dc * 151;
            for (int j = 0; j < 150; j++) acc += sm.qp.xl[w][j] * wr[j];
        }
        __syncthreads();
        // chunk 1: Wl columns 150..299
        for (int j = tid; j < 4500; j += 256)
            sm.qp.Wc[(j / 150) * 151 + (j % 150)] = Wl[(size_t)(j / 150) * 300 + 150 + (j % 150)];
        __syncthreads();
        if (jh == 1) {
            const float* wr = sm.qp.Wc + dc * 151;
            for (int j = 0; j < 150; j++) acc += sm.qp.xl[w][150 + j] * wr[j];
        }
        acc += __shfl_xor(acc, 1, 64);      // first half + second half (proj3 order)
        if (jh == 0 && d < DD) {
            if (s == 0) pl[t * (BB * DD) + b * DD + d] = acc;
            sm.qp.rr[w][d] = acc;
        }
        // LN + q (kvq0 q-path verbatim)
        const float* g  = n1g + (size_t)po * 30;
        const float* bb = n1b + (size_t)po * 30;
        float xval = (lane < 30) ? sm.qp.rr[w][lane] : 0.f;
        float mean = wsum(xval) * (1.f / 30.f);
        float dv = (lane < 30) ? (xval - mean) : 0.f;
        float var = wsum(dv * dv) * (1.f / 30.f);
        float inv = rsqrtf(var + 1e-5f);
        if (lane < 30) sm.qp.xn[w][lane] = dv * inv * g[lane] + bb[lane];
        if (lane < 30) {
            const float* wr = sm.qp.iwS + lane * 30;
            float acc2 = 0.f;
            #pragma unroll 6
            for (int j = 0; j < 30; j++) acc2 += wr[j] * sm.qp.xn[w][j];
            acc2 = (acc2 + in_b[po * 90 + lane]) * 0.40824829046386307f;   // HD^-0.5
            int i = b * HH + lane / HD, hd = lane % HD;
            size_t rw = (((size_t)s * NI + i) * TT + t) * 8;
            q[rw + hd] = (_Float16)acc2;
            if (hd < 2) q[rw + 6 + hd] = (_Float16)0.f;
        }
    }
}

// Score kernel (R7 text — best measured): block = (s, head i, g); one head's
// q/k/v staged f16 in LDS; 4 waves x 2 a's. max3 trees + es folded into acc7.
__global__ __launch_bounds__(256, 4) void score_kernel(
    const _Float16* __restrict__ q, const _Float16* __restrict__ k_all,
    const _Float16* __restrict__ v_all, int l, float* __restrict__ attn) {
    int blk = blockIdx.x;                   // [0, 1520)
    int s = blk / 760;
    int rem = blk % 760;
    int i = rem / 19;
    int g = rem % 19;
    int tid = threadIdx.x;
    int wv = tid >> 6, lane = tid & 63;
    int lo = lane & 31, hf = lane >> 5;
    int po = s * LL + l;

    __shared__ __align__(16) _Float16 qsh[NR * RSTR];
    __shared__ __align__(16) _Float16 ksh[NR * RSTR];
    __shared__ __align__(16) _Float16 vsh[NR * RSTR];

    const _Float16* qg = q + (size_t)(s * NI + i) * TT * 8;
    const _Float16* kg = k_all + ((size_t)po * NI + i) * TT * 8;
    const _Float16* vg = v_all + ((size_t)po * NI + i) * TT * 8;
    half8 z8;
    #pragma unroll
    for (int t = 0; t < 8; t++) z8[t] = (_Float16)0.f;
    for (int r = tid; r < NR; r += 256) {
        half8 qa = z8, ka = z8, va = z8;
        if (r < TT) {
            qa = *(const half8*)&qg[r * 8];
            ka = *(const half8*)&kg[r * 8];
            va = *(const half8*)&vg[r * 8];
        }
        *(half8*)&qsh[r * RSTR] = qa;
        *(half8*)&ksh[r * RSTR] = ka;
        *(half8*)&vsh[r * RSTR] = va;
    }
    __syncthreads();
    if (wv == 0) {   // vbar row (pre-scaled by 1/150) into vsh row 150
        float v6[6] = {0.f, 0.f, 0.f, 0.f, 0.f, 0.f};
        for (int c = lane; c < TT; c += 64) {
            #pragma unroll
            for (int t = 0; t < 6; t++) v6[t] += (float)vsh[c * RSTR + t];
        }
        #pragma unroll
        for (int m = 32; m > 0; m >>= 1) {
            #pragma unroll
            for (int t = 0; t < 6; t++) v6[t] += __shfl_xor(v6[t], m, 64);
        }
        if (lane < 6) vsh[TT * RSTR + lane] = (_Float16)(v6[lane] * (1.f / TT));
    }
    __syncthreads();

    f32x16 zacc;
    #pragma unroll
    for (int j = 0; j < 16; j++) zacc[j] = 0.f;

    half8 bfrag[5], vhalf[5];
    #pragma unroll
    for (int nt = 0; nt < 5; nt++) {
        int rr = nt * 32 + lo;
        int rc = rr < 151 ? rr : 151;          // 150 = vbar, 151 = zeros
        half8 kf = *(const half8*)&ksh[rc * RSTR];
        half8 vf = *(const half8*)&vsh[rc * RSTR];
        bfrag[nt] = hf ? z8 : kf;
        vhalf[nt] = hf ? z8 : vf;
    }

    for (int ap = 0; ap < 2; ap++) {
        int a = g * 8 + wv * 2 + ap;
        if (a >= TT) break;
        half8 qav = *(const half8*)&qsh[a * RSTR];
        half8 afrag[5];
        #pragma unroll
        for (int nt = 0; nt < 5; nt++) afrag[nt] = vhalf[nt] * qav;  // v_pk_mul_f16

        float fsc[5];
        #pragma unroll
        for (int nb = 0; nb < 5; nb++) {
            float tm[4];
            #pragma unroll
            for (int ma = 0; ma < 4; ma++) {
                f32x16 acc = __builtin_amdgcn_mfma_f32_32x32x16_f16(afrag[ma], bfrag[nb], zacc, 0, 0, 0);
                float u0 = max3f(acc[0], acc[1], acc[2]);
                float u1 = max3f(acc[3], acc[4], acc[5]);
                float u2 = max3f(acc[6], acc[7], acc[8]);
                float u3 = max3f(acc[9], acc[10], acc[11]);
                float u4 = max3f(acc[12], acc[13], acc[14]);
                tm[ma] = fmaxf(max3f(u0, u1, u2), max3f(u3, u4, acc[15]));
            }
            f32x16 a4 = __builtin_amdgcn_mfma_f32_32x32x16_f16(afrag[4], bfrag[nb], zacc, 0, 0, 0);
            float t0 = max3f(a4[0], a4[1], a4[2]);
            float t1 = max3f(a4[3], a4[4], a4[5]);
            float t2 = max3f(a4[6], a4[7], a4[8]);
            float ext = (hf == 0) ? fmaxf(a4[10], a4[11]) : -INFINITY;
            float rest = fmaxf(a4[9], ext);
            float m4 = fmaxf(max3f(t0, t1, t2), rest);
            float rm = fmaxf(max3f(tm[0], tm[1], tm[2]), fmaxf(tm[3], m4));
            float om = __shfl_xor(a4[10], 32, 64);
            float mn = hf ? a4[10] : om;
            rm = fmaxf(rm, __shfl_xor(rm, 32, 64));
            int bcol = nb * 32 + lo;
            fsc[nb] = (bcol < TT) ? (mn + rm) : -INFINITY;
        }
        float m = fmaxf(max3f(fsc[0], fsc[1], fsc[2]), fmaxf(fsc[3], fsc[4]));
        #pragma unroll
        for (int msk = 16; msk > 0; msk >>= 1) m = fmaxf(m, __shfl_xor(m, msk, 64));
        float e[5], es = 0.f;
        #pragma unroll
        for (int nb = 0; nb < 5; nb++) { e[nb] = __expf(fsc[nb] - m); es += e[nb]; }
        float acc7[7] = {0.f, 0.f, 0.f, 0.f, 0.f, 0.f, 0.f};
        acc7[6] = es;
        #pragma unroll
        for (int nb = 0; nb < 5; nb++) {
            int bcol = nb * 32 + lo;
            int bi = (bcol < TT) ? bcol : 0;
            float wgt = e[nb];
            half8 qrow = *(const half8*)&qsh[bi * RSTR];
            #pragma unroll
            for (int t = 0; t < 6; t++) acc7[t] += wgt * (float)qrow[t];
        }
        #pragma unroll
        for (int msk = 16; msk > 0; msk >>= 1) {
            #pragma unroll
            for (int t = 0; t < 7; t++) acc7[t] += __shfl_xor(acc7[t], msk, 64);
        }
        if (lane == 0) {
            float inv = 1.f / acc7[6];
            int bo = i / HH, ho = i % HH;
            float* dst = attn + (size_t)s * ROWF + a * (BB * DD) + bo * DD + ho * HD;
            #pragma unroll
            for (int t = 0; t < 6; t++) dst[t] = acc7[t] * inv;
        }
    }
}

// FFN for layer l + q-projection for layer l+1. w2 dot split across lane pairs
// (60 MACs + combine instead of a 120-MAC serial chain).
__global__ __launch_bounds__(256) void ffnlnq_kernel(
    const float* __restrict__ attn, const float* __restrict__ pl,
    const float* __restrict__ out_w, const float* __restrict__ out_b,
    const float* __restrict__ l1w, const float* __restrict__ l1b,
    const float* __restrict__ l2w, const float* __restrict__ l2b,
    const float* __restrict__ n2g, const float* __restrict__ n2b,
    const float* __restrict__ in_w, const float* __restrict__ in_b,
    const float* __restrict__ n1g, const float* __restrict__ n1b,
    int l, int has_next,
    float* __restrict__ h, _Float16* __restrict__ q) {
    int blk = blockIdx.x;                   // [0,600)
    int s = blk / 300;
    int w = threadIdx.x >> 6, lane = threadIdx.x & 63;
    int tb = (blk % 300) * 4 + w;           // [0,1200)
    int t = tb / BB, b = tb % BB;
    int po = s * LL + l;
    const float* ow = out_w + (size_t)po * 900;
    const float* ob = out_b + (size_t)po * 30;
    const float* w1 = l1w + (size_t)po * 3600;
    const float* b1 = l1b + (size_t)po * 120;
    const float* w2 = l2w + (size_t)po * 3600;
    const float* b2 = l2b + (size_t)po * 30;
    const float* g2 = n2g + (size_t)po * 30;
    const float* bb2 = n2b + (size_t)po * 30;
    __shared__ float owS[900];
    __shared__ float w1T[30 * 128];
    __shared__ float w2S[30 * 121];
    __shared__ float iwqS[900];
    __shared__ float arS[4][30], xnS[4][32], hidS[4][120], xqS[4][30];
    for (int j = threadIdx.x; j < 900; j += 256) owS[j] = ow[j];
    for (int j = threadIdx.x; j < 3600; j += 256) w1T[(j % 30) * 128 + (j / 30)] = w1[j];
    for (int j = threadIdx.x; j < 3600; j += 256) w2S[(j / 120) * 121 + (j % 120)] = w2[j];
    if (has_next) {
        const float* iwq = in_w + (size_t)(po + 1) * 2700;
        for (int j = threadIdx.x; j < 900; j += 256) iwqS[j] = iwq[j];
    }
    __syncthreads();
    float* hrow = h + (size_t)s * ROWF + (size_t)tb * 30;
    const float* res = (l == 0) ? (pl + (size_t)tb * 30) : hrow;
    const float* arow = attn + (size_t)s * ROWF + (size_t)tb * 30;
    if (lane < 30) arS[w][lane] = arow[lane];
    float x1v = 0.f;
    if (lane < 30) {
        const float* wr = owS + lane * 30;
        float acc = 0.f;
        #pragma unroll 6
        for (int j = 0; j < 30; j++) acc += wr[j] * arS[w][j];
        x1v = res[lane] + acc + ob[lane];
    }
    float mean = wsum(x1v) * (1.f / 30.f);
    float dv = (lane < 30) ? (x1v - mean) : 0.f;
    float var = wsum(dv * dv) * (1.f / 30.f);
    float inv = rsqrtf(var + 1e-5f);
    if (lane < 30) xnS[w][lane] = dv * inv * g2[lane] + bb2[lane];
    for (int o = lane; o < 120; o += 64) {
        float acc = 0.f;
        #pragma unroll 6
        for (int j = 0; j < 30; j++) acc += w1T[j * 128 + o] * xnS[w][j];
        hidS[w][o] = fmaxf(acc + b1[o], 0.f);
    }
    // w2 dot: lane pairs (d = lane>>1), 60 MACs each, combine, gather to lane d
    float acc2p = 0.f;
    if (lane < 60) {
        int d2 = lane >> 1, part = lane & 1;
        const float* wr = w2S + d2 * 121;
        int j0 = part ? 60 : 0, j1 = part ? 120 : 60;
        #pragma unroll 6
        for (int j = j0; j < j1; j++) acc2p += wr[j] * hidS[w][j];
        acc2p += __shfl_xor(acc2p, 1, 64);   // lane 2d holds full sum (0..59 + 60..119)
    }
    int srcl = (lane < 30) ? (lane << 1) : 0;
    float accG = __shfl(acc2p, srcl, 64);
    float newh = 0.f;
    if (lane < 30) {
        newh = x1v + accG + b2[lane];
        hrow[lane] = newh;
    }
    if (has_next) {
        const float* g1 = n1g + (size_t)(po + 1) * 30;
        const float* bb1 = n1b + (size_t)(po + 1) * 30;
        const float* ibq = in_b + (size_t)(po + 1) * 90;
        float mean2 = wsum(newh) * (1.f / 30.f);
        float dv2 = (lane < 30) ? (newh - mean2) : 0.f;
        float var2 = wsum(dv2 * dv2) * (1.f / 30.f);
        float inv2 = rsqrtf(var2 + 1e-5f);
        if (lane < 30) xqS[w][lane] = dv2 * inv2 * g1[lane] + bb1[lane];
        if (lane < 30) {
            const float* wr = iwqS + lane * 30;
            float acc = 0.f;
            #pragma unroll 6
            for (int j = 0; j < 30; j++) acc += wr[j] * xqS[w][j];
            acc = (acc + ibq[lane]) * 0.40824829046386307f;
            int i = b * HH + lane / HD, hd = lane % HD;
            size_t rw = (((size_t)s * NI + i) * TT + t) * 8;
            q[rw + hd] = (_Float16)acc;
            if (hd < 2) q[rw + 6 + hd] = (_Float16)0.f;
        }
    }
}

// Final head: last_hs, proj MLP + residual, scalar out. Writes all 488 outputs.
__global__ __launch_bounds__(256) void head_kernel(
    const float* __restrict__ h,
    const float* __restrict__ p1w, const float* __restrict__ p1b,
    const float* __restrict__ p2w, const float* __restrict__ p2b,
    const float* __restrict__ ow, const float* __restrict__ ob,
    float* __restrict__ out) {
    int tid = threadIdx.x;
    __shared__ float lh[480], hid[480], pr[480];
    for (int idx = tid; idx < 480; idx += 256) {
        int b = idx / 60, j = idx % 60;
        int s = j / 30, d = j % 30;
        float vv = h[(size_t)s * ROWF + 149 * (BB * DD) + b * DD + d];
        lh[idx] = vv;
        out[8 + idx] = vv;   // last_hs
    }
    __syncthreads();
    for (int idx = tid; idx < 480; idx += 256) {
        int b = idx / 60, o = idx % 60;
        const float* wr = p1w + o * 60;
        float acc = p1b[o];
        for (int j = 0; j < 60; j++) acc += wr[j] * lh[b * 60 + j];
        hid[idx] = fmaxf(acc, 0.f);
    }
    __syncthreads();
    for (int idx = tid; idx < 480; idx += 256) {
        int b = idx / 60, d = idx % 60;
        const float* wr = p2w + d * 60;
        float acc = p2b[d];
        for (int j = 0; j < 60; j++) acc += wr[j] * hid[b * 60 + j];
        pr[idx] = acc + lh[idx];
    }
    __syncthreads();
    if (tid < 8) {
        float acc = ob[0];
        for (int j = 0; j < 60; j++) acc += pr[tid * 60 + j] * ow[j];
        out[tid] = acc;      // out
    }
}

extern "C" void kernel_launch(void* const* d_in, const int* in_sizes, int n_in,
                              void* d_out, int out_size, void* d_ws, size_t ws_size,
                              hipStream_t stream) {
    const float* x_l   = (const float*)d_in[0];
    const float* x_a   = (const float*)d_in[1];
    const float* x_v   = (const float*)d_in[2];
    const float* Wl    = (const float*)d_in[3];
    const float* Wa    = (const float*)d_in[4];
    const float* Wv    = (const float*)d_in[5];
    const float* in_w  = (const float*)d_in[6];
    const float* in_b  = (const float*)d_in[7];
    const float* out_w = (const float*)d_in[8];
    const float* out_b = (const float*)d_in[9];
    const float* l1w   = (const float*)d_in[10];
    const float* l1b   = (const float*)d_in[11];
    const float* l2w   = (const float*)d_in[12];
    const float* l2b   = (const float*)d_in[13];
    const float* n1g   = (const float*)d_in[14];
    const float* n1b   = (const float*)d_in[15];
    const float* n2g   = (const float*)d_in[16];
    const float* n2b   = (const float*)d_in[17];
    const float* p1w   = (const float*)d_in[18];
    const float* p1b   = (const float*)d_in[19];
    const float* p2w   = (const float*)d_in[20];
    const float* p2b   = (const float*)d_in[21];
    const float* oww   = (const float*)d_in[22];
    const float* obb   = (const float*)d_in[23];

    float* ws = (float*)d_ws;
    float* pl    = ws;             // 36000
    float* h     = ws + 36000;     // 72000  [2][T][B][D]
    float* at    = ws + 108000;    // 72000
    _Float16* qh = (_Float16*)(ws + 180000);   // [2][NI][TT][8] halves (48000 f)
    _Float16* kh = (_Float16*)(ws + 228000);   // [6][NI][TT][8] halves (144000 f)
    _Float16* vh = (_Float16*)(ws + 372000);   // [6][NI][TT][8] halves (144000 f)

    front_kernel<<<2400, 256, 0, stream>>>(x_l, x_a, x_v, Wl, Wa, Wv,
                                           in_w, in_b, n1g, n1b,
                                           pl, kh, vh, qh);
    for (int l = 0; l < LL; l++) {
        score_kernel<<<1520, 256, 0, stream>>>(qh, kh, vh, l, at);
        ffnlnq_kernel<<<600, 256, 0, stream>>>(at, pl, out_w, out_b, l1w, l1b, l2w, l2b,
                                               n2g, n2b, in_w, in_b, n1g, n1b,
                                               l, (l < LL - 1) ? 1 : 0, h, qh);
    }
    head_kernel<<<1, 256, 0, stream>>>(h, p1w, p1b, p2w, p2b, oww, obb, (float*)d_out);
}

// Round 10
// 232.107 us; speedup vs baseline: 1.0439x; 1.0439x over previous
//
#include <hip/hip_runtime.h>
#include <math.h>

// Model dims
#define BB 8
#define TT 150
#define DD 30
#define HH 5
#define HD 6
#define LL 3
#define NI 40            // B*H heads per stream
#define ROWF (TT*BB*DD)  // 36000 floats per [T,B,D] buffer
#define RSTR 8           // padded LDS row stride in halves (16B -> ds_read_b128)
#define NR 152           // padded row count (150 data + vbar + zero)

typedef _Float16 half8 __attribute__((ext_vector_type(8)));
typedef float f32x16 __attribute__((ext_vector_type(16)));

__device__ __forceinline__ float wsum(float v) {
    #pragma unroll
    for (int m = 32; m > 0; m >>= 1) v += __shfl_xor(v, m, 64);
    return v;
}

__device__ __forceinline__ float max3f(float a, float b, float c) {
    return fmaxf(fmaxf(a, b), c);   // clang fuses to v_max3_f32; max is exactly associative
}

// All three k=1 conv projections. 300 blocks per input; weights staged in LDS.
__global__ __launch_bounds__(256) void proj3_kernel(
    const float* __restrict__ x_l, const float* __restrict__ x_a, const float* __restrict__ x_v,
    const float* __restrict__ Wl, const float* __restrict__ Wa, const float* __restrict__ Wv,
    float* __restrict__ pl, float* __restrict__ pa, float* __restrict__ pv) {
    int blk = blockIdx.x;                   // [0,900)
    int which = blk / 300;
    int w = threadIdx.x >> 6, lane = threadIdx.x & 63;
    int rowu = (blk % 300) * 4 + w;         // [0,1200)
    int t = rowu / BB, b = rowu % BB;
    const float* x = which == 0 ? x_l : (which == 1 ? x_a : x_v);
    const float* W = which == 0 ? Wl : (which == 1 ? Wa : Wv);
    float* out = which == 0 ? pl : (which == 1 ? pa : pv);
    int Cin = which == 0 ? 300 : (which == 1 ? 74 : 35);
    int cst = Cin | 1;                      // odd LDS row stride -> bank spread
    __shared__ float WS[30 * 301];
    __shared__ float xr[4][304];
    for (int j = threadIdx.x; j < DD * Cin; j += 256)
        WS[(j / Cin) * cst + (j % Cin)] = W[j];
    const float* xp = x + ((size_t)b * TT + t) * Cin;
    for (int j = lane; j < Cin; j += 64) xr[w][j] = xp[j];
    __syncthreads();
    int d = lane >> 1, jh = lane & 1;
    int h1 = Cin >> 1;
    int j0 = jh ? h1 : 0, j1 = jh ? Cin : h1;
    const float* wr = WS + (size_t)(d < DD ? d : 0) * cst;
    float acc = 0.f;
    for (int j = j0; j < j1; j++) acc += xr[w][j] * wr[j];
    acc += __shfl_xor(acc, 1, 64);
    if (jh == 0 && d < DD) out[t * (BB * DD) + b * DD + d] = acc;
}

// Merged: blocks [0,1800) compute k,v for all 6 (s,l); blocks [1800,2400) q for layer 0.
// q/k/v are written as f16 rows padded to 8 halves (16B). R2-verified (absmax 0).
__global__ __launch_bounds__(256) void kvq0_kernel(
    const float* __restrict__ pl, const float* __restrict__ pa, const float* __restrict__ pv,
    const float* __restrict__ in_w, const float* __restrict__ in_b,
    const float* __restrict__ n1g, const float* __restrict__ n1b,
    _Float16* __restrict__ k_all, _Float16* __restrict__ v_all, _Float16* __restrict__ q) {
    int blk = blockIdx.x;                   // [0,2400)
    int w = threadIdx.x >> 6, lane = threadIdx.x & 63;
    __shared__ float iwS[1800];
    __shared__ float xn[4][2][30];
    if (blk < 1800) {
        int po = blk / 300;                 // s*LL+l
        int s = po / LL;
        int tb = (blk % 300) * 4 + w;       // [0,1200)
        int t = tb / BB, b = tb % BB;
        const float* xk = (s == 0) ? pa : pv;
        const float* xv = (s == 0) ? pv : pa;
        const float* iw = in_w + (size_t)po * 2700 + 900;   // k,v rows 30..89
        const float* ib = in_b + (size_t)po * 90;
        const float* g  = n1g + (size_t)po * 30;
        const float* bb = n1b + (size_t)po * 30;
        for (int j = threadIdx.x; j < 1800; j += 256) iwS[j] = iw[j];
        const float* rows[2] = { xk + (size_t)tb * 30, xv + (size_t)tb * 30 };
        for (int r = 0; r < 2; r++) {
            float xval = (lane < 30) ? rows[r][lane] : 0.f;
            float mean = wsum(xval) * (1.f / 30.f);
            float dv = (lane < 30) ? (xval - mean) : 0.f;
            float var = wsum(dv * dv) * (1.f / 30.f);
            float inv = rsqrtf(var + 1e-5f);
            if (lane < 30) xn[w][r][lane] = dv * inv * g[lane] + bb[lane];
        }
        __syncthreads();
        if (lane < 60) {
            int which = lane / 30, dd = lane % 30;
            const float* wr = iwS + lane * 30;
            const float* xv2 = xn[w][which];
            float acc = 0.f;
            #pragma unroll 6
            for (int j = 0; j < 30; j++) acc += wr[j] * xv2[j];
            acc += ib[30 + lane];
            int i = b * HH + dd / HD, hd = dd % HD;
            _Float16* dst = which ? v_all : k_all;
            size_t row = (((size_t)po * NI + i) * TT + t) * 8;
            dst[row + hd] = (_Float16)acc;
            if (hd < 2) dst[row + 6 + hd] = (_Float16)0.f;   // zero the pad halves
        }
    } else {
        int r2 = blk - 1800;                // [0,600)
        int s = r2 / 300;
        int tb = (r2 % 300) * 4 + w;
        int t = tb / BB, b = tb % BB;
        int po = s * LL;                    // layer 0
        const float* iw = in_w + (size_t)po * 2700;   // q rows 0..29
        const float* ib = in_b + (size_t)po * 90;
        const float* g  = n1g + (size_t)po * 30;
        const float* bb = n1b + (size_t)po * 30;
        for (int j = threadIdx.x; j < 900; j += 256) iwS[j] = iw[j];
        const float* row = pl + (size_t)tb * 30;
        float xval = (lane < 30) ? row[lane] : 0.f;
        float mean = wsum(xval) * (1.f / 30.f);
        float dv = (lane < 30) ? (xval - mean) : 0.f;
        float var = wsum(dv * dv) * (1.f / 30.f);
        float inv = rsqrtf(var + 1e-5f);
        if (lane < 30) xn[w][0][lane] = dv * inv * g[lane] + bb[lane];
        __syncthreads();
        if (lane < 30) {
            const float* wr = iwS + lane * 30;
            float acc = 0.f;
            #pragma unroll 6
            for (int j = 0; j < 30; j++) acc += wr[j] * xn[w][0][j];
            acc = (acc + ib[lane]) * 0.40824829046386307f;   // HD^-0.5
            int i = b * HH + lane / HD, hd = lane % HD;
            size_t rw = (((size_t)s * NI + i) * TT + t) * 8;
            q[rw + hd] = (_Float16)acc;
            if (hd < 2) q[rw + 6 + hd] = (_Float16)0.f;
        }
    }
}

// Score kernel (R7 text — best measured) + vectorized vbar read (bit-identical).
__global__ __launch_bounds__(256, 4) void score_kernel(
    const _Float16* __restrict__ q, const _Float16* __restrict__ k_all,
    const _Float16* __restrict__ v_all, int l, float* __restrict__ attn) {
    int blk = blockIdx.x;                   // [0, 1520)
    int s = blk / 760;
    int rem = blk % 760;
    int i = rem / 19;
    int g = rem % 19;
    int tid = threadIdx.x;
    int wv = tid >> 6, lane = tid & 63;
    int lo = lane & 31, hf = lane >> 5;
    int po = s * LL + l;

    __shared__ __align__(16) _Float16 qsh[NR * RSTR];
    __shared__ __align__(16) _Float16 ksh[NR * RSTR];
    __shared__ __align__(16) _Float16 vsh[NR * RSTR];

    const _Float16* qg = q + (size_t)(s * NI + i) * TT * 8;
    const _Float16* kg = k_all + ((size_t)po * NI + i) * TT * 8;
    const _Float16* vg = v_all + ((size_t)po * NI + i) * TT * 8;
    half8 z8;
    #pragma unroll
    for (int t = 0; t < 8; t++) z8[t] = (_Float16)0.f;
    for (int r = tid; r < NR; r += 256) {
        half8 qa = z8, ka = z8, va = z8;
        if (r < TT) {
            qa = *(const half8*)&qg[r * 8];
            ka = *(const half8*)&kg[r * 8];
            va = *(const half8*)&vg[r * 8];
        }
        *(half8*)&qsh[r * RSTR] = qa;
        *(half8*)&ksh[r * RSTR] = ka;
        *(half8*)&vsh[r * RSTR] = va;
    }
    __syncthreads();
    if (wv == 0) {   // vbar row (pre-scaled by 1/150) into vsh row 150
        float v6[6] = {0.f, 0.f, 0.f, 0.f, 0.f, 0.f};
        for (int c = lane; c < TT; c += 64) {
            half8 vrow = *(const half8*)&vsh[c * RSTR];   // one ds_read_b128
            #pragma unroll
            for (int t = 0; t < 6; t++) v6[t] += (float)vrow[t];
        }
        #pragma unroll
        for (int m = 32; m > 0; m >>= 1) {
            #pragma unroll
            for (int t = 0; t < 6; t++) v6[t] += __shfl_xor(v6[t], m, 64);
        }
        if (lane < 6) vsh[TT * RSTR + lane] = (_Float16)(v6[lane] * (1.f / TT));
    }
    __syncthreads();

    f32x16 zacc;
    #pragma unroll
    for (int j = 0; j < 16; j++) zacc[j] = 0.f;

    half8 bfrag[5], vhalf[5];
    #pragma unroll
    for (int nt = 0; nt < 5; nt++) {
        int rr = nt * 32 + lo;
        int rc = rr < 151 ? rr : 151;          // 150 = vbar, 151 = zeros
        half8 kf = *(const half8*)&ksh[rc * RSTR];
        half8 vf = *(const half8*)&vsh[rc * RSTR];
        bfrag[nt] = hf ? z8 : kf;
        vhalf[nt] = hf ? z8 : vf;
    }

    for (int ap = 0; ap < 2; ap++) {
        int a = g * 8 + wv * 2 + ap;
        if (a >= TT) break;
        half8 qav = *(const half8*)&qsh[a * RSTR];
        half8 afrag[5];
        #pragma unroll
        for (int nt = 0; nt < 5; nt++) afrag[nt] = vhalf[nt] * qav;  // v_pk_mul_f16

        float fsc[5];
        #pragma unroll
        for (int nb = 0; nb < 5; nb++) {
            float tm[4];
            #pragma unroll
            for (int ma = 0; ma < 4; ma++) {
                f32x16 acc = __builtin_amdgcn_mfma_f32_32x32x16_f16(afrag[ma], bfrag[nb], zacc, 0, 0, 0);
                float u0 = max3f(acc[0], acc[1], acc[2]);
                float u1 = max3f(acc[3], acc[4], acc[5]);
                float u2 = max3f(acc[6], acc[7], acc[8]);
                float u3 = max3f(acc[9], acc[10], acc[11]);
                float u4 = max3f(acc[12], acc[13], acc[14]);
                tm[ma] = fmaxf(max3f(u0, u1, u2), max3f(u3, u4, acc[15]));
            }
            f32x16 a4 = __builtin_amdgcn_mfma_f32_32x32x16_f16(afrag[4], bfrag[nb], zacc, 0, 0, 0);
            float t0 = max3f(a4[0], a4[1], a4[2]);
            float t1 = max3f(a4[3], a4[4], a4[5]);
            float t2 = max3f(a4[6], a4[7], a4[8]);
            float ext = (hf == 0) ? fmaxf(a4[10], a4[11]) : -INFINITY;
            float rest = fmaxf(a4[9], ext);
            float m4 = fmaxf(max3f(t0, t1, t2), rest);
            float rm = fmaxf(max3f(tm[0], tm[1], tm[2]), fmaxf(tm[3], m4));
            float om = __shfl_xor(a4[10], 32, 64);
            float mn = hf ? a4[10] : om;
            rm = fmaxf(rm, __shfl_xor(rm, 32, 64));
            int bcol = nb * 32 + lo;
            fsc[nb] = (bcol < TT) ? (mn + rm) : -INFINITY;
        }
        float m = fmaxf(max3f(fsc[0], fsc[1], fsc[2]), fmaxf(fsc[3], fsc[4]));
        #pragma unroll
        for (int msk = 16; msk > 0; msk >>= 1) m = fmaxf(m, __shfl_xor(m, msk, 64));
        float e[5], es = 0.f;
        #pragma unroll
        for (int nb = 0; nb < 5; nb++) { e[nb] = __expf(fsc[nb] - m); es += e[nb]; }
        float acc7[7] = {0.f, 0.f, 0.f, 0.f, 0.f, 0.f, 0.f};
        acc7[6] = es;
        #pragma unroll
        for (int nb = 0; nb < 5; nb++) {
            int bcol = nb * 32 + lo;
            int bi = (bcol < TT) ? bcol : 0;
            float wgt = e[nb];
            half8 qrow = *(const half8*)&qsh[bi * RSTR];
            #pragma unroll
            for (int t = 0; t < 6; t++) acc7[t] += wgt * (float)qrow[t];
        }
        #pragma unroll
        for (int msk = 16; msk > 0; msk >>= 1) {
            #pragma unroll
            for (int t = 0; t < 7; t++) acc7[t] += __shfl_xor(acc7[t], msk, 64);
        }
        if (lane == 0) {
            float inv = 1.f / acc7[6];
            int bo = i / HH, ho = i % HH;
            float* dst = attn + (size_t)s * ROWF + a * (BB * DD) + bo * DD + ho * HD;
            #pragma unroll
            for (int t = 0; t < 6; t++) dst[t] = acc7[t] * inv;
        }
    }
}

// FFN for layer l + q-projection for layer l+1 (exact per-row fusion). R2/R7-verified.
__global__ __launch_bounds__(256) void ffnlnq_kernel(
    const float* __restrict__ attn, const float* __restrict__ pl,
    const float* __restrict__ out_w, const float* __restrict__ out_b,
    const float* __restrict__ l1w, const float* __restrict__ l1b,
    const float* __restrict__ l2w, const float* __restrict__ l2b,
    const float* __restrict__ n2g, const float* __restrict__ n2b,
    const float* __restrict__ in_w, const float* __restrict__ in_b,
    const float* __restrict__ n1g, const float* __restrict__ n1b,
    int l, int has_next,
    float* __restrict__ h, _Float16* __restrict__ q) {
    int blk = blockIdx.x;                   // [0,600)
    int s = blk / 300;
    int w = threadIdx.x >> 6, lane = threadIdx.x & 63;
    int tb = (blk % 300) * 4 + w;           // [0,1200)
    int t = tb / BB, b = tb % BB;
    int po = s * LL + l;
    const float* ow = out_w + (size_t)po * 900;
    const float* ob = out_b + (size_t)po * 30;
    const float* w1 = l1w + (size_t)po * 3600;
    const float* b1 = l1b + (size_t)po * 120;
    const float* w2 = l2w + (size_t)po * 3600;
    const float* b2 = l2b + (size_t)po * 30;
    const float* g2 = n2g + (size_t)po * 30;
    const float* bb2 = n2b + (size_t)po * 30;
    __shared__ float owS[900];
    __shared__ float w1T[30 * 128];
    __shared__ float w2S[30 * 121];
    __shared__ float iwqS[900];
    __shared__ float arS[4][30], xnS[4][32], hidS[4][120], xqS[4][30];
    for (int j = threadIdx.x; j < 900; j += 256) owS[j] = ow[j];
    for (int j = threadIdx.x; j < 3600; j += 256) w1T[(j % 30) * 128 + (j / 30)] = w1[j];
    for (int j = threadIdx.x; j < 3600; j += 256) w2S[(j / 120) * 121 + (j % 120)] = w2[j];
    if (has_next) {
        const float* iwq = in_w + (size_t)(po + 1) * 2700;
        for (int j = threadIdx.x; j < 900; j += 256) iwqS[j] = iwq[j];
    }
    __syncthreads();
    float* hrow = h + (size_t)s * ROWF + (size_t)tb * 30;
    const float* res = (l == 0) ? (pl + (size_t)tb * 30) : hrow;
    const float* arow = attn + (size_t)s * ROWF + (size_t)tb * 30;
    if (lane < 30) arS[w][lane] = arow[lane];
    float x1v = 0.f;
    if (lane < 30) {
        const float* wr = owS + lane * 30;
        float acc = 0.f;
        #pragma unroll 6
        for (int j = 0; j < 30; j++) acc += wr[j] * arS[w][j];
        x1v = res[lane] + acc + ob[lane];
    }
    float mean = wsum(x1v) * (1.f / 30.f);
    float dv = (lane < 30) ? (x1v - mean) : 0.f;
    float var = wsum(dv * dv) * (1.f / 30.f);
    float inv = rsqrtf(var + 1e-5f);
    if (lane < 30) xnS[w][lane] = dv * inv * g2[lane] + bb2[lane];
    for (int o = lane; o < 120; o += 64) {
        float acc = 0.f;
        #pragma unroll 6
        for (int j = 0; j < 30; j++) acc += w1T[j * 128 + o] * xnS[w][j];
        hidS[w][o] = fmaxf(acc + b1[o], 0.f);
    }
    float newh = 0.f;
    if (lane < 30) {
        const float* wr = w2S + lane * 121;
        float acc = 0.f;
        #pragma unroll 8
        for (int j = 0; j < 120; j++) acc += wr[j] * hidS[w][j];
        newh = x1v + acc + b2[lane];
        hrow[lane] = newh;
    }
    if (has_next) {
        const float* g1 = n1g + (size_t)(po + 1) * 30;
        const float* bb1 = n1b + (size_t)(po + 1) * 30;
        const float* ibq = in_b + (size_t)(po + 1) * 90;
        float mean2 = wsum(newh) * (1.f / 30.f);
        float dv2 = (lane < 30) ? (newh - mean2) : 0.f;
        float var2 = wsum(dv2 * dv2) * (1.f / 30.f);
        float inv2 = rsqrtf(var2 + 1e-5f);
        if (lane < 30) xqS[w][lane] = dv2 * inv2 * g1[lane] + bb1[lane];
        if (lane < 30) {
            const float* wr = iwqS + lane * 30;
            float acc = 0.f;
            #pragma unroll 6
            for (int j = 0; j < 30; j++) acc += wr[j] * xqS[w][j];
            acc = (acc + ibq[lane]) * 0.40824829046386307f;
            int i = b * HH + lane / HD, hd = lane % HD;
            size_t rw = (((size_t)s * NI + i) * TT + t) * 8;
            q[rw + hd] = (_Float16)acc;
            if (hd < 2) q[rw + 6 + hd] = (_Float16)0.f;
        }
    }
}

// Final head: last_hs, proj MLP + residual, scalar out. Writes all 488 outputs.
__global__ __launch_bounds__(256) void head_kernel(
    const float* __restrict__ h,
    const float* __restrict__ p1w, const float* __restrict__ p1b,
    const float* __restrict__ p2w, const float* __restrict__ p2b,
    const float* __restrict__ ow, const float* __restrict__ ob,
    float* __restrict__ out) {
    int tid = threadIdx.x;
    __shared__ float lh[480], hid[480], pr[480];
    for (int idx = tid; idx < 480; idx += 256) {
        int b = idx / 60, j = idx % 60;
        int s = j / 30, d = j % 30;
        float vv = h[(size_t)s * ROWF + 149 * (BB * DD) + b * DD + d];
        lh[idx] = vv;
        out[8 + idx] = vv;   // last_hs
    }
    __syncthreads();
    for (int idx = tid; idx < 480; idx += 256) {
        int b = idx / 60, o = idx % 60;
        const float* wr = p1w + o * 60;
        float acc = p1b[o];
        for (int j = 0; j < 60; j++) acc += wr[j] * lh[b * 60 + j];
        hid[idx] = fmaxf(acc, 0.f);
    }
    __syncthreads();
    for (int idx = tid; idx < 480; idx += 256) {
        int b = idx / 60, d = idx % 60;
        const float* wr = p2w + d * 60;
        float acc = p2b[d];
        for (int j = 0; j < 60; j++) acc += wr[j] * hid[b * 60 + j];
        pr[idx] = acc + lh[idx];
    }
    __syncthreads();
    if (tid < 8) {
        float acc = ob[0];
        for (int j = 0; j < 60; j++) acc += pr[tid * 60 + j] * ow[j];
        out[tid] = acc;      // out
    }
}

extern "C" void kernel_launch(void* const* d_in, const int* in_sizes, int n_in,
                              void* d_out, int out_size, void* d_ws, size_t ws_size,
                              hipStream_t stream) {
    const float* x_l   = (const float*)d_in[0];
    const float* x_a   = (const float*)d_in[1];
    const float* x_v   = (const float*)d_in[2];
    const float* Wl    = (const float*)d_in[3];
    const float* Wa    = (const float*)d_in[4];
    const float* Wv    = (const float*)d_in[5];
    const float* in_w  = (const float*)d_in[6];
    const float* in_b  = (const float*)d_in[7];
    const float* out_w = (const float*)d_in[8];
    const float* out_b = (const float*)d_in[9];
    const float* l1w   = (const float*)d_in[10];
    const float* l1b   = (const float*)d_in[11];
    const float* l2w   = (const float*)d_in[12];
    const float* l2b   = (const float*)d_in[13];
    const float* n1g   = (const float*)d_in[14];
    const float* n1b   = (const float*)d_in[15];
    const float* n2g   = (const float*)d_in[16];
    const float* n2b   = (const float*)d_in[17];
    const float* p1w   = (const float*)d_in[18];
    const float* p1b   = (const float*)d_in[19];
    const float* p2w   = (const float*)d_in[20];
    const float* p2b   = (const float*)d_in[21];
    const float* oww   = (const float*)d_in[22];
    const float* obb   = (const float*)d_in[23];

    float* ws = (float*)d_ws;
    float* pl    = ws;             // 36000
    float* pa    = ws + 36000;     // 36000
    float* pv    = ws + 72000;     // 36000
    float* h     = ws + 108000;    // 72000  [2][T][B][D]
    float* at    = ws + 180000;    // 72000
    _Float16* qh = (_Float16*)(ws + 252000);   // [2][NI][TT][8] halves (48000 f)
    _Float16* kh = (_Float16*)(ws + 300000);   // [6][NI][TT][8] halves (144000 f)
    _Float16* vh = (_Float16*)(ws + 444000);   // [6][NI][TT][8] halves (144000 f)

    proj3_kernel<<<900, 256, 0, stream>>>(x_l, x_a, x_v, Wl, Wa, Wv, pl, pa, pv);
    kvq0_kernel<<<2400, 256, 0, stream>>>(pl, pa, pv, in_w, in_b, n1g, n1b,
                                          kh, vh, qh);
    for (int l = 0; l < LL; l++) {
        score_kernel<<<1520, 256, 0, stream>>>(qh, kh, vh, l, at);
        ffnlnq_kernel<<<600, 256, 0, stream>>>(at, pl, out_w, out_b, l1w, l1b, l2w, l2b,
                                               n2g, n2b, in_w, in_b, n1g, n1b,
                                               l, (l < LL - 1) ? 1 : 0, h, qh);
    }
    head_kernel<<<1, 256, 0, stream>>>(h, p1w, p1b, p2w, p2b, oww, obb, (float*)d_out);
}